// Round 1
// baseline (2409.442 us; speedup 1.0000x reference)
//
#include <hip/hip_runtime.h>
#include <cstddef>

#define T_SEQ 2048
#define D_EMB 768
#define NHEAD 12
#define DH 64

// ---------------------------------------------------------------------------
// GEMM: out = x @ W^T + bias.  x:[M,768], W:[768,768] row-major (W[n][k]).
// Tile 64x64, BK=32, 256 threads, each thread 4x4 outputs.
// Two epilogue variants: QKV (scatter to [B,H,T,64]) and flat [M,768].
// ---------------------------------------------------------------------------

__global__ __launch_bounds__(256)
void proj_qkv_kernel(const float* __restrict__ x,
                     const float* __restrict__ Wq, const float* __restrict__ bq,
                     const float* __restrict__ Wk, const float* __restrict__ bk,
                     const float* __restrict__ Wv, const float* __restrict__ bv,
                     float* __restrict__ qo, float* __restrict__ ko,
                     float* __restrict__ vo)
{
    const int which = blockIdx.z;
    const float* __restrict__ W    = (which == 0) ? Wq : (which == 1) ? Wk : Wv;
    const float* __restrict__ bias = (which == 0) ? bq : (which == 1) ? bk : bv;
    float* __restrict__ out        = (which == 0) ? qo : (which == 1) ? ko : vo;

    __shared__ float As[32][65];   // [k][m], +1 pad: store/load conflict-free
    __shared__ float Bs[32][65];   // [k][n]

    const int m0 = blockIdx.x * 64;
    const int n0 = blockIdx.y * 64;
    const int tid = threadIdx.x;
    const int tx = tid & 15;       // col group 0..15
    const int ty = tid >> 4;       // row group 0..15

    float acc[4][4] = {};

    for (int k0 = 0; k0 < D_EMB; k0 += 32) {
        const int c  = tid & 31;   // 32 consecutive floats per 32 lanes: coalesced
        const int r0 = tid >> 5;   // 0..7
#pragma unroll
        for (int i = 0; i < 8; ++i) {
            const int r = r0 + i * 8;
            As[c][r] = x[(size_t)(m0 + r) * D_EMB + k0 + c];
            Bs[c][r] = W[(size_t)(n0 + r) * D_EMB + k0 + c];
        }
        __syncthreads();
#pragma unroll
        for (int kk = 0; kk < 32; ++kk) {
            float a[4], b[4];
#pragma unroll
            for (int i = 0; i < 4; ++i) a[i] = As[kk][ty + 16 * i];
#pragma unroll
            for (int j = 0; j < 4; ++j) b[j] = Bs[kk][tx + 16 * j];
#pragma unroll
            for (int i = 0; i < 4; ++i)
#pragma unroll
                for (int j = 0; j < 4; ++j)
                    acc[i][j] += a[i] * b[j];
        }
        __syncthreads();
    }

#pragma unroll
    for (int i = 0; i < 4; ++i) {
        const int m = m0 + ty + 16 * i;
        const int b = m >> 11;          // / 2048
        const int t = m & 2047;
#pragma unroll
        for (int j = 0; j < 4; ++j) {
            const int n  = n0 + tx + 16 * j;
            const int h  = n >> 6;
            const int dh = n & 63;
            out[(((size_t)(b * NHEAD + h) * T_SEQ) + t) * DH + dh] =
                acc[i][j] + bias[n];
        }
    }
}

__global__ __launch_bounds__(256)
void proj_out_kernel(const float* __restrict__ x,
                     const float* __restrict__ W,
                     const float* __restrict__ bias,
                     float* __restrict__ out)
{
    __shared__ float As[32][65];
    __shared__ float Bs[32][65];

    const int m0 = blockIdx.x * 64;
    const int n0 = blockIdx.y * 64;
    const int tid = threadIdx.x;
    const int tx = tid & 15;
    const int ty = tid >> 4;

    float acc[4][4] = {};

    for (int k0 = 0; k0 < D_EMB; k0 += 32) {
        const int c  = tid & 31;
        const int r0 = tid >> 5;
#pragma unroll
        for (int i = 0; i < 8; ++i) {
            const int r = r0 + i * 8;
            As[c][r] = x[(size_t)(m0 + r) * D_EMB + k0 + c];
            Bs[c][r] = W[(size_t)(n0 + r) * D_EMB + k0 + c];
        }
        __syncthreads();
#pragma unroll
        for (int kk = 0; kk < 32; ++kk) {
            float a[4], b[4];
#pragma unroll
            for (int i = 0; i < 4; ++i) a[i] = As[kk][ty + 16 * i];
#pragma unroll
            for (int j = 0; j < 4; ++j) b[j] = Bs[kk][tx + 16 * j];
#pragma unroll
            for (int i = 0; i < 4; ++i)
#pragma unroll
                for (int j = 0; j < 4; ++j)
                    acc[i][j] += a[i] * b[j];
        }
        __syncthreads();
    }

#pragma unroll
    for (int i = 0; i < 4; ++i) {
        const int m = m0 + ty + 16 * i;
#pragma unroll
        for (int j = 0; j < 4; ++j) {
            const int n = n0 + tx + 16 * j;
            out[(size_t)m * D_EMB + n] = acc[i][j] + bias[n];
        }
    }
}

// ---------------------------------------------------------------------------
// Flash-style causal attention, fp32.
// Block = 4 consecutive query rows of one (b,h); wave w owns row t0+w.
// K/V staged in LDS in 64-key tiles (shared by the 4 waves).
// QK^T: lane = key slot (score per lane).  PV: lane = output dim.
// Online softmax state per wave: running max m, sum ssum; y held as 1 VGPR/lane.
// ---------------------------------------------------------------------------
__global__ __launch_bounds__(256)
void attn_kernel(const float* __restrict__ q, const float* __restrict__ k,
                 const float* __restrict__ v, float* __restrict__ y)
{
    __shared__ float Ks[64][65];   // +1 pad: (lane*65+d)%32 spreads banks
    __shared__ float Vs[64][65];
    __shared__ float qs[4][64];
    __shared__ float ps[4][64];

    const int bh   = blockIdx.y;          // 0..47  (b*12+h)
    const int w    = threadIdx.x >> 6;    // wave 0..3
    const int lane = threadIdx.x & 63;
    const int t    = blockIdx.x * 4 + w;  // query row

    qs[w][lane] = q[((size_t)bh * T_SEQ + t) * DH + lane];

    float mrun = -1e30f, ssum = 0.f, yacc = 0.f;
    const int ntiles = (blockIdx.x * 4 + 3) / 64 + 1;   // block-uniform
    const float scale = 0.125f;                         // 1/sqrt(64)

    for (int j = 0; j < ntiles; ++j) {
        const int kb = j * 64;
        const float* kt = k + ((size_t)bh * T_SEQ + kb) * DH;
        const float* vt = v + ((size_t)bh * T_SEQ + kb) * DH;
#pragma unroll
        for (int i = 0; i < 16; ++i) {
            const int idx = threadIdx.x + i * 256;
            const int r = idx >> 6, c = idx & 63;
            Ks[r][c] = kt[(size_t)r * DH + c];
            Vs[r][c] = vt[(size_t)r * DH + c];
        }
        __syncthreads();

        // score for key kb+lane
        float s = -1e30f;
        const bool live = (kb + lane <= t);
        if (live) {
            float a = 0.f;
#pragma unroll
            for (int d = 0; d < 64; ++d)
                a += qs[w][d] * Ks[lane][d];   // qs broadcast; Ks 2-way (free)
            s = a * scale;
        }
        // wave-wide max
        float tmax = s;
#pragma unroll
        for (int off = 32; off >= 1; off >>= 1)
            tmax = fmaxf(tmax, __shfl_xor(tmax, off, 64));
        const float mnew = fmaxf(mrun, tmax);
        const float corr = __expf(mrun - mnew);
        yacc *= corr;
        ssum *= corr;
        const float p = live ? __expf(s - mnew) : 0.f;
        ps[w][lane] = p;
        float psum = p;
#pragma unroll
        for (int off = 32; off >= 1; off >>= 1)
            psum += __shfl_xor(psum, off, 64);
        ssum += psum;
        mrun = mnew;

        // PV: yacc(dim=lane) += sum_l p[l] * V[l][lane]
#pragma unroll 8
        for (int l = 0; l < 64; ++l)
            yacc += ps[w][l] * Vs[l][lane];    // ps broadcast; Vs 2-way (free)
        __syncthreads();
    }

    const int b = bh / NHEAD, h = bh % NHEAD;
    y[((size_t)(b * T_SEQ + t)) * D_EMB + h * DH + lane] = yacc / ssum;
}

// ---------------------------------------------------------------------------
extern "C" void kernel_launch(void* const* d_in, const int* in_sizes, int n_in,
                              void* d_out, int out_size, void* d_ws, size_t ws_size,
                              hipStream_t stream)
{
    const float* x  = (const float*)d_in[0];
    const float* Wq = (const float*)d_in[1];
    const float* bq = (const float*)d_in[2];
    const float* Wk = (const float*)d_in[3];
    const float* bk = (const float*)d_in[4];
    const float* Wv = (const float*)d_in[5];
    const float* bv = (const float*)d_in[6];
    const float* Wp = (const float*)d_in[7];
    const float* bp = (const float*)d_in[8];
    float* out = (float*)d_out;

    // workspace: q,k,v in [B,H,T,64] + y in [B,T,768]; 4 x 25.2 MB = ~101 MB
    const size_t per = (size_t)4 * NHEAD * T_SEQ * DH;   // 6291456 floats
    float* q = (float*)d_ws;
    float* kk = q + per;
    float* vv = kk + per;
    float* y  = vv + per;

    dim3 gProj(8192 / 64, D_EMB / 64, 3);   // 128 x 12 x 3
    proj_qkv_kernel<<<gProj, 256, 0, stream>>>(x, Wq, bq, Wk, bk, Wv, bv, q, kk, vv);

    dim3 gAttn(T_SEQ / 4, 4 * NHEAD);       // 512 x 48
    attn_kernel<<<gAttn, 256, 0, stream>>>(q, kk, vv, y);

    dim3 gOut(8192 / 64, D_EMB / 64);       // 128 x 12
    proj_out_kernel<<<gOut, 256, 0, stream>>>(y, Wp, bp, out);
}

// Round 4
// 1058.852 us; speedup vs baseline: 2.2755x; 2.2755x over previous
//
#include <hip/hip_runtime.h>
#include <hip/hip_bf16.h>
#include <cstddef>

#define T_SEQ 2048
#define D_EMB 768
#define NHEAD 12
#define DH 64

typedef __attribute__((ext_vector_type(8))) short short8;
typedef __attribute__((ext_vector_type(4))) float floatx4;

__device__ __forceinline__ unsigned short f2bf(float f) {
    unsigned u = __float_as_uint(f);
    u = (u + 0x7FFFu + ((u >> 16) & 1u)) >> 16;
    return (unsigned short)u;
}

// ---------------------------------------------------------------------------
// QKV projection: out = x @ W^T + bias (fp32 compute), epilogues emit bf16.
//   q: [B,H,T,64] bf16, pre-scaled by 1/sqrt(Dh)=0.125
//   k: [B,H,T,64] bf16
//   v: [B,H,64,T] bf16  (TRANSPOSED, via LDS tile so global writes coalesce)
// ---------------------------------------------------------------------------
__global__ __launch_bounds__(256)
void proj_qkv_kernel(const float* __restrict__ x,
                     const float* __restrict__ Wq, const float* __restrict__ bq,
                     const float* __restrict__ Wk, const float* __restrict__ bk,
                     const float* __restrict__ Wv, const float* __restrict__ bv,
                     __hip_bfloat16* __restrict__ qo,
                     __hip_bfloat16* __restrict__ ko,
                     __hip_bfloat16* __restrict__ vo)
{
    const int which = blockIdx.z;
    const float* __restrict__ W    = (which == 0) ? Wq : (which == 1) ? Wk : Wv;
    const float* __restrict__ bias = (which == 0) ? bq : (which == 1) ? bk : bv;

    __shared__ float As[32][65];
    __shared__ float Bs[32][65];
    __shared__ float Vt[64][65];   // transpose staging for V epilogue

    const int m0 = blockIdx.x * 64;
    const int n0 = blockIdx.y * 64;
    const int tid = threadIdx.x;
    const int tx = tid & 15;
    const int ty = tid >> 4;

    float acc[4][4] = {};

    for (int k0 = 0; k0 < D_EMB; k0 += 32) {
        const int c  = tid & 31;
        const int r0 = tid >> 5;
#pragma unroll
        for (int i = 0; i < 8; ++i) {
            const int r = r0 + i * 8;
            As[c][r] = x[(size_t)(m0 + r) * D_EMB + k0 + c];
            Bs[c][r] = W[(size_t)(n0 + r) * D_EMB + k0 + c];
        }
        __syncthreads();
#pragma unroll
        for (int kk = 0; kk < 32; ++kk) {
            float a[4], b[4];
#pragma unroll
            for (int i = 0; i < 4; ++i) a[i] = As[kk][ty + 16 * i];
#pragma unroll
            for (int j = 0; j < 4; ++j) b[j] = Bs[kk][tx + 16 * j];
#pragma unroll
            for (int i = 0; i < 4; ++i)
#pragma unroll
                for (int j = 0; j < 4; ++j)
                    acc[i][j] += a[i] * b[j];
        }
        __syncthreads();
    }

    if (which < 2) {
        __hip_bfloat16* out = (which == 0) ? qo : ko;
        const float scale = (which == 0) ? 0.125f : 1.0f;
#pragma unroll
        for (int i = 0; i < 4; ++i) {
            const int m = m0 + ty + 16 * i;
            const int b = m >> 11;
            const int t = m & 2047;
#pragma unroll
            for (int j = 0; j < 4; ++j) {
                const int n  = n0 + tx + 16 * j;
                const int h  = n >> 6;
                const int dh = n & 63;
                const float v = (acc[i][j] + bias[n]) * scale;
                unsigned short bits = f2bf(v);
                out[(((size_t)(b * NHEAD + h) * T_SEQ) + t) * DH + dh] =
                    *reinterpret_cast<__hip_bfloat16*>(&bits);
            }
        }
    } else {
        // V: transpose 64x64 tile through LDS, write [B,H,64,T] coalesced
#pragma unroll
        for (int i = 0; i < 4; ++i)
#pragma unroll
            for (int j = 0; j < 4; ++j) {
                const int n = n0 + tx + 16 * j;
                Vt[tx + 16 * j][ty + 16 * i] = acc[i][j] + bias[n];
            }
        __syncthreads();
        const int row  = tid >> 2;        // dh local 0..63
        const int toff = (tid & 3) * 16;  // 16 t-values per thread
        const int b  = m0 >> 11;
        const int t0 = m0 & 2047;
        const int h  = blockIdx.y;        // n0 = h*64
        __hip_bfloat16* dst = vo + (((size_t)(b * NHEAD + h) * DH) + row) * T_SEQ
                              + t0 + toff;
        unsigned short bits[16];
#pragma unroll
        for (int u = 0; u < 16; ++u) bits[u] = f2bf(Vt[row][toff + u]);
#pragma unroll
        for (int u = 0; u < 16; ++u)
            dst[u] = *reinterpret_cast<__hip_bfloat16*>(&bits[u]);
    }
}

// ---------------------------------------------------------------------------
// Output projection (fp32) — unchanged.
// ---------------------------------------------------------------------------
__global__ __launch_bounds__(256)
void proj_out_kernel(const float* __restrict__ x,
                     const float* __restrict__ W,
                     const float* __restrict__ bias,
                     float* __restrict__ out)
{
    __shared__ float As[32][65];
    __shared__ float Bs[32][65];

    const int m0 = blockIdx.x * 64;
    const int n0 = blockIdx.y * 64;
    const int tid = threadIdx.x;
    const int tx = tid & 15;
    const int ty = tid >> 4;

    float acc[4][4] = {};

    for (int k0 = 0; k0 < D_EMB; k0 += 32) {
        const int c  = tid & 31;
        const int r0 = tid >> 5;
#pragma unroll
        for (int i = 0; i < 8; ++i) {
            const int r = r0 + i * 8;
            As[c][r] = x[(size_t)(m0 + r) * D_EMB + k0 + c];
            Bs[c][r] = W[(size_t)(n0 + r) * D_EMB + k0 + c];
        }
        __syncthreads();
#pragma unroll
        for (int kk = 0; kk < 32; ++kk) {
            float a[4], b[4];
#pragma unroll
            for (int i = 0; i < 4; ++i) a[i] = As[kk][ty + 16 * i];
#pragma unroll
            for (int j = 0; j < 4; ++j) b[j] = Bs[kk][tx + 16 * j];
#pragma unroll
            for (int i = 0; i < 4; ++i)
#pragma unroll
                for (int j = 0; j < 4; ++j)
                    acc[i][j] += a[i] * b[j];
        }
        __syncthreads();
    }

#pragma unroll
    for (int i = 0; i < 4; ++i) {
        const int m = m0 + ty + 16 * i;
#pragma unroll
        for (int j = 0; j < 4; ++j) {
            const int n = n0 + tx + 16 * j;
            out[(size_t)m * D_EMB + n] = acc[i][j] + bias[n];
        }
    }
}

// ---------------------------------------------------------------------------
// MFMA flash attention (bf16 inputs, fp32 accumulate), causal.
// Block = 4 independent waves; wave owns 16 q-rows. No __syncthreads.
// Per 64-key tile: 8 MFMA for S=QK^T, wave-local online softmax (C-layout:
// q-row=4g+r, key=lane&15), P->A-frag via swizzled per-wave LDS roundtrip,
// 8 MFMA for PV with V pre-transposed [Dh][T].
// ---------------------------------------------------------------------------
__global__ __launch_bounds__(256)
void attn_mfma_kernel(const __hip_bfloat16* __restrict__ qb,
                      const __hip_bfloat16* __restrict__ kbp,
                      const __hip_bfloat16* __restrict__ vtb,
                      float* __restrict__ y)
{
    // per-wave P buffer: [kf][q][slot][i] bf16 = 2*16*4*8*2 = 2048 B
    __shared__ __align__(16) char Pbuf[4][2048];

    const int bh   = blockIdx.y;
    const int w    = threadIdx.x >> 6;
    const int lane = threadIdx.x & 63;
    const int g    = lane >> 4;
    const int c    = lane & 15;
    const int q0   = blockIdx.x * 64 + w * 16;

    const __hip_bfloat16* Qp = qb  + (size_t)bh * T_SEQ * DH;
    const __hip_bfloat16* Kp = kbp + (size_t)bh * T_SEQ * DH;
    const __hip_bfloat16* Vp = vtb + (size_t)bh * DH * T_SEQ;
    char* pw = Pbuf[w];

    // Q fragments hoisted (A-frag: row q=c, k = 32*kf + 8g + i)
    short8 qf0 = *reinterpret_cast<const short8*>(Qp + (size_t)(q0 + c) * DH + 8 * g);
    short8 qf1 = *reinterpret_cast<const short8*>(Qp + (size_t)(q0 + c) * DH + 32 + 8 * g);

    floatx4 yacc[4];
#pragma unroll
    for (int n = 0; n < 4; ++n) yacc[n] = (floatx4){0.f, 0.f, 0.f, 0.f};
    float mrun[4], lsum[4];
#pragma unroll
    for (int r = 0; r < 4; ++r) { mrun[r] = -1e30f; lsum[r] = 0.f; }

    const int nkb = ((q0 + 15) >> 6) + 1;

    for (int jb = 0; jb < nkb; ++jb) {
        const int kb0 = jb * 64;

        // ---- S = Q K^T (16 q-rows x 64 keys) ----
        floatx4 s[4];
#pragma unroll
        for (int n = 0; n < 4; ++n) s[n] = (floatx4){0.f, 0.f, 0.f, 0.f};
#pragma unroll
        for (int n = 0; n < 4; ++n) {
            const __hip_bfloat16* kr = Kp + (size_t)(kb0 + 16 * n + c) * DH + 8 * g;
            short8 kf0 = *reinterpret_cast<const short8*>(kr);
            short8 kf1 = *reinterpret_cast<const short8*>(kr + 32);
            s[n] = __builtin_amdgcn_mfma_f32_16x16x32_bf16(qf0, kf0, s[n], 0, 0, 0);
            s[n] = __builtin_amdgcn_mfma_f32_16x16x32_bf16(qf1, kf1, s[n], 0, 0, 0);
        }

        // ---- causal mask (diagonal tiles only; block-uniform branch) ----
        if (kb0 + 63 > q0) {
#pragma unroll
            for (int n = 0; n < 4; ++n)
#pragma unroll
                for (int r = 0; r < 4; ++r)
                    if (kb0 + 16 * n + c > q0 + 4 * g + r) s[n][r] = -1e30f;
        }

        // ---- online softmax (per q-row = 4g+r) ----
        float mt[4];
#pragma unroll
        for (int r = 0; r < 4; ++r)
            mt[r] = fmaxf(fmaxf(s[0][r], s[1][r]), fmaxf(s[2][r], s[3][r]));
#pragma unroll
        for (int off = 8; off >= 1; off >>= 1)
#pragma unroll
            for (int r = 0; r < 4; ++r)
                mt[r] = fmaxf(mt[r], __shfl_xor(mt[r], off, 64));

        float corr[4];
#pragma unroll
        for (int r = 0; r < 4; ++r) {
            const float mn = fmaxf(mrun[r], mt[r]);
            corr[r] = __expf(mrun[r] - mn);
            mrun[r] = mn;
        }
#pragma unroll
        for (int n = 0; n < 4; ++n)
#pragma unroll
            for (int r = 0; r < 4; ++r) yacc[n][r] *= corr[r];

        float rs[4] = {0.f, 0.f, 0.f, 0.f};
#pragma unroll
        for (int n = 0; n < 4; ++n) {
            const int kf = n >> 1;
            const int gk = 2 * (n & 1) + (c >> 3);
            const int slot = gk ^ g;                  // swizzle by q>>2 (=g)
#pragma unroll
            for (int r = 0; r < 4; ++r) {
                const float p = __expf(s[n][r] - mrun[r]);
                rs[r] += p;
                const int qrow = 4 * g + r;
                unsigned short bits = f2bf(p);
                *reinterpret_cast<unsigned short*>(
                    pw + kf * 1024 + qrow * 64 + (slot << 4) + (c & 7) * 2) = bits;
            }
        }
#pragma unroll
        for (int off = 8; off >= 1; off >>= 1)
#pragma unroll
            for (int r = 0; r < 4; ++r) rs[r] += __shfl_xor(rs[r], off, 64);
#pragma unroll
        for (int r = 0; r < 4; ++r) lsum[r] = lsum[r] * corr[r] + rs[r];

        // drain P writes (wave-local; no barrier needed)
        asm volatile("s_waitcnt lgkmcnt(0)" ::: "memory");
        __builtin_amdgcn_sched_barrier(0);

        // ---- P A-frags: lane reads q=c, keys 32kf+8g..+7 (swizzled slot) ----
        const int rslot = g ^ ((c >> 2) & 3);
        short8 pf0 = *reinterpret_cast<const short8*>(pw + c * 64 + (rslot << 4));
        short8 pf1 = *reinterpret_cast<const short8*>(pw + 1024 + c * 64 + (rslot << 4));

        // ---- PV: Y += P V  (V^T layout: B-frag contiguous) ----
#pragma unroll
        for (int nd = 0; nd < 4; ++nd) {
            const __hip_bfloat16* vr = Vp + (size_t)(16 * nd + c) * T_SEQ + kb0 + 8 * g;
            short8 vf0 = *reinterpret_cast<const short8*>(vr);
            short8 vf1 = *reinterpret_cast<const short8*>(vr + 32);
            yacc[nd] = __builtin_amdgcn_mfma_f32_16x16x32_bf16(pf0, vf0, yacc[nd], 0, 0, 0);
            yacc[nd] = __builtin_amdgcn_mfma_f32_16x16x32_bf16(pf1, vf1, yacc[nd], 0, 0, 0);
        }
    }

    // ---- epilogue: y[b, q, h*64+d] = yacc / lsum ----
    const int b = bh / NHEAD, h = bh % NHEAD;
    float inv[4];
#pragma unroll
    for (int r = 0; r < 4; ++r) inv[r] = 1.f / lsum[r];
#pragma unroll
    for (int n = 0; n < 4; ++n)
#pragma unroll
        for (int r = 0; r < 4; ++r)
            y[((size_t)b * T_SEQ + q0 + 4 * g + r) * D_EMB + h * DH + 16 * n + c] =
                yacc[n][r] * inv[r];
}

// ---------------------------------------------------------------------------
extern "C" void kernel_launch(void* const* d_in, const int* in_sizes, int n_in,
                              void* d_out, int out_size, void* d_ws, size_t ws_size,
                              hipStream_t stream)
{
    const float* x  = (const float*)d_in[0];
    const float* Wq = (const float*)d_in[1];
    const float* bq = (const float*)d_in[2];
    const float* Wk = (const float*)d_in[3];
    const float* bk = (const float*)d_in[4];
    const float* Wv = (const float*)d_in[5];
    const float* bv = (const float*)d_in[6];
    const float* Wp = (const float*)d_in[7];
    const float* bp = (const float*)d_in[8];
    float* out = (float*)d_out;

    // workspace: q,k (bf16 [B,H,T,64]) + vt (bf16 [B,H,64,T]) + y (fp32 [B,T,768])
    const size_t per = (size_t)4 * NHEAD * T_SEQ * DH;   // 6291456 elements
    __hip_bfloat16* qbf  = (__hip_bfloat16*)d_ws;
    __hip_bfloat16* kbf  = qbf + per;
    __hip_bfloat16* vtbf = kbf + per;
    float* yws = (float*)(vtbf + per);

    dim3 gProj(8192 / 64, D_EMB / 64, 3);
    proj_qkv_kernel<<<gProj, 256, 0, stream>>>(x, Wq, bq, Wk, bk, Wv, bv,
                                               qbf, kbf, vtbf);

    dim3 gAttn(T_SEQ / 64, 4 * NHEAD);       // 32 x 48, 4 waves/block
    attn_mfma_kernel<<<gAttn, 256, 0, stream>>>(qbf, kbf, vtbf, yws);

    dim3 gOut(8192 / 64, D_EMB / 64);
    proj_out_kernel<<<gOut, 256, 0, stream>>>(yws, Wp, bp, out);
}

// Round 5
// 513.035 us; speedup vs baseline: 4.6964x; 2.0639x over previous
//
#include <hip/hip_runtime.h>
#include <hip/hip_bf16.h>
#include <cstddef>

#define T_SEQ 2048
#define D_EMB 768
#define NHEAD 12
#define DH 64

typedef __attribute__((ext_vector_type(8))) short short8;
typedef __attribute__((ext_vector_type(4))) short short4v;
typedef __attribute__((ext_vector_type(4))) float floatx4;

__device__ __forceinline__ unsigned short f2bf(float f) {
    unsigned u = __float_as_uint(f);
    u = (u + 0x7FFFu + ((u >> 16) & 1u)) >> 16;
    return (unsigned short)u;
}

__device__ __forceinline__ void gload16(const void* g, void* l) {
    __builtin_amdgcn_global_load_lds(
        (const __attribute__((address_space(1))) void*)g,
        (__attribute__((address_space(3))) void*)l, 16, 0, 0);
}

// ---------------------------------------------------------------------------
// Cast fp32 -> bf16: x [8192x768], Wq/Wk/Wv packed into one [2304][768], Wp.
// 1 thread = 8 elements. Exact grid: 1081344 chunks = 4224 blocks x 256.
// ---------------------------------------------------------------------------
__global__ __launch_bounds__(256)
void cast_bf16_kernel(const float* __restrict__ x,
                      const float* __restrict__ Wq, const float* __restrict__ Wk,
                      const float* __restrict__ Wv, const float* __restrict__ Wp,
                      __hip_bfloat16* __restrict__ xb,
                      __hip_bfloat16* __restrict__ wqkvb,
                      __hip_bfloat16* __restrict__ wpb)
{
    const int ci = blockIdx.x * 256 + threadIdx.x;   // chunk of 8 elements
    const float* src;
    __hip_bfloat16* dst;
    size_t off;
    if (ci < 786432) {                    // x: 6291456/8
        src = x; dst = xb; off = (size_t)ci * 8;
    } else {
        const int r  = ci - 786432;
        const int wi = r / 73728;         // 589824/8 per weight
        const int ro = r - wi * 73728;
        off = (size_t)ro * 8;
        src = (wi == 0) ? Wq : (wi == 1) ? Wk : (wi == 2) ? Wv : Wp;
        dst = (wi < 3) ? wqkvb + (size_t)wi * 589824 : wpb;
    }
    const float4* s4 = reinterpret_cast<const float4*>(src + off);
    const float4 f0 = s4[0], f1 = s4[1];
    unsigned short us[8] = { f2bf(f0.x), f2bf(f0.y), f2bf(f0.z), f2bf(f0.w),
                             f2bf(f1.x), f2bf(f1.y), f2bf(f1.z), f2bf(f1.w) };
    *reinterpret_cast<short8*>(dst + off) = *reinterpret_cast<const short8*>(us);
}

// ---------------------------------------------------------------------------
// bf16 MFMA GEMM: C = A @ B^T + bias.  A:[M][768], B:[N][768] bf16 row-major.
// 128x128 tile, BK=64, 256 thr / 4 waves (2x2, each 64x64), m97 structure:
// global_load_lds width-16 staging, single LDS buffer, 2 barriers per K-step.
// MODE 0: QKV epilogue (N=2304: q scaled+scatter / k scatter / v transposed).
// MODE 1: plain fp32 out + bias.
// ---------------------------------------------------------------------------
template<int MODE>
__global__ __launch_bounds__(256)
void gemm_bf16_mfma(const __hip_bfloat16* __restrict__ A,
                    const __hip_bfloat16* __restrict__ Bm,
                    const float* __restrict__ b0, const float* __restrict__ b1,
                    const float* __restrict__ b2,
                    __hip_bfloat16* __restrict__ qo,
                    __hip_bfloat16* __restrict__ ko,
                    __hip_bfloat16* __restrict__ vo,
                    float* __restrict__ out)
{
    __shared__ __align__(16) __hip_bfloat16 As[128 * 64];
    __shared__ __align__(16) __hip_bfloat16 Bs[128 * 64];

    const int tid  = threadIdx.x;
    const int w    = tid >> 6, lane = tid & 63;
    const int g    = lane >> 4, c = lane & 15;
    const int m0   = blockIdx.x * 128, n0 = blockIdx.y * 128;
    const int wr   = w >> 1, wc = w & 1;
    const int srow = lane >> 3;         // 0..7 within 8-row chunk
    const int scol = (lane & 7) * 8;    // k offset in elements (16B granular)

    floatx4 acc[4][4];
#pragma unroll
    for (int mi = 0; mi < 4; ++mi)
#pragma unroll
        for (int ni = 0; ni < 4; ++ni)
            acc[mi][ni] = (floatx4){0.f, 0.f, 0.f, 0.f};

    for (int kt = 0; kt < 12; ++kt) {
        const int k0 = kt * 64;
#pragma unroll
        for (int j = 0; j < 4; ++j) {
            const int ch = w * 4 + j;   // wave-uniform chunk id (8 rows / 1KB)
            gload16(A  + (size_t)(m0 + ch * 8 + srow) * D_EMB + k0 + scol,
                    (char*)As + ch * 1024);
            gload16(Bm + (size_t)(n0 + ch * 8 + srow) * D_EMB + k0 + scol,
                    (char*)Bs + ch * 1024);
        }
        __syncthreads();                // drains vmcnt: staging visible
#pragma unroll
        for (int kk = 0; kk < 2; ++kk) {
            short8 af[4], bfr[4];
#pragma unroll
            for (int mi = 0; mi < 4; ++mi)
                af[mi] = *reinterpret_cast<const short8*>(
                    As + (wr * 64 + mi * 16 + c) * 64 + kk * 32 + g * 8);
#pragma unroll
            for (int ni = 0; ni < 4; ++ni)
                bfr[ni] = *reinterpret_cast<const short8*>(
                    Bs + (wc * 64 + ni * 16 + c) * 64 + kk * 32 + g * 8);
#pragma unroll
            for (int mi = 0; mi < 4; ++mi)
#pragma unroll
                for (int ni = 0; ni < 4; ++ni)
                    acc[mi][ni] = __builtin_amdgcn_mfma_f32_16x16x32_bf16(
                        af[mi], bfr[ni], acc[mi][ni], 0, 0, 0);
        }
        __syncthreads();                // LDS free for next staging
    }

    if (MODE == 0) {
        const int which = n0 / 768;                  // block-uniform (128|768)
        const int nb    = n0 - which * 768 + wc * 64;
        const float* bias = (which == 0) ? b0 : (which == 1) ? b1 : b2;
        if (which < 2) {
            __hip_bfloat16* dst = (which == 0) ? qo : ko;
            const float scale = (which == 0) ? 0.125f : 1.0f;
#pragma unroll
            for (int mi = 0; mi < 4; ++mi) {
                const int m = m0 + wr * 64 + mi * 16 + 4 * g;
                const int b = m >> 11, t = m & 2047;
#pragma unroll
                for (int ni = 0; ni < 4; ++ni) {
                    const int n7 = nb + ni * 16 + c;
                    const int h = n7 >> 6, dh = n7 & 63;
                    const float bval = bias[n7];
                    const size_t base =
                        ((size_t)(b * NHEAD + h) * T_SEQ + t) * DH + dh;
#pragma unroll
                    for (int rr = 0; rr < 4; ++rr) {
                        unsigned short bits =
                            f2bf((acc[mi][ni][rr] + bval) * scale);
                        dst[base + (size_t)rr * DH] =
                            *reinterpret_cast<__hip_bfloat16*>(&bits);
                    }
                }
            }
        } else {
            // V: write transposed [B,H,64,T]; 4 consecutive t per lane -> 8B store
#pragma unroll
            for (int mi = 0; mi < 4; ++mi) {
                const int m = m0 + wr * 64 + mi * 16 + 4 * g;
                const int b = m >> 11, t = m & 2047;
#pragma unroll
                for (int ni = 0; ni < 4; ++ni) {
                    const int n7 = nb + ni * 16 + c;
                    const int h = n7 >> 6, dh = n7 & 63;
                    const float bval = bias[n7];
                    unsigned short us[4];
#pragma unroll
                    for (int rr = 0; rr < 4; ++rr)
                        us[rr] = f2bf(acc[mi][ni][rr] + bval);
                    *reinterpret_cast<short4v*>(
                        vo + ((size_t)(b * NHEAD + h) * DH + dh) * T_SEQ + t) =
                        *reinterpret_cast<const short4v*>(us);
                }
            }
        }
    } else {
#pragma unroll
        for (int mi = 0; mi < 4; ++mi) {
            const int m = m0 + wr * 64 + mi * 16 + 4 * g;
#pragma unroll
            for (int ni = 0; ni < 4; ++ni) {
                const int n = n0 + wc * 64 + ni * 16 + c;
                const float bval = b0[n];
#pragma unroll
                for (int rr = 0; rr < 4; ++rr)
                    out[(size_t)(m + rr) * D_EMB + n] = acc[mi][ni][rr] + bval;
            }
        }
    }
}

// ---------------------------------------------------------------------------
// MFMA flash attention (unchanged from Round 4 except bf16 output).
// ---------------------------------------------------------------------------
__global__ __launch_bounds__(256)
void attn_mfma_kernel(const __hip_bfloat16* __restrict__ qb,
                      const __hip_bfloat16* __restrict__ kbp,
                      const __hip_bfloat16* __restrict__ vtb,
                      __hip_bfloat16* __restrict__ y)
{
    __shared__ __align__(16) char Pbuf[4][2048];

    const int bh   = blockIdx.y;
    const int w    = threadIdx.x >> 6;
    const int lane = threadIdx.x & 63;
    const int g    = lane >> 4;
    const int c    = lane & 15;
    const int q0   = blockIdx.x * 64 + w * 16;

    const __hip_bfloat16* Qp = qb  + (size_t)bh * T_SEQ * DH;
    const __hip_bfloat16* Kp = kbp + (size_t)bh * T_SEQ * DH;
    const __hip_bfloat16* Vp = vtb + (size_t)bh * DH * T_SEQ;
    char* pw = Pbuf[w];

    short8 qf0 = *reinterpret_cast<const short8*>(Qp + (size_t)(q0 + c) * DH + 8 * g);
    short8 qf1 = *reinterpret_cast<const short8*>(Qp + (size_t)(q0 + c) * DH + 32 + 8 * g);

    floatx4 yacc[4];
#pragma unroll
    for (int n = 0; n < 4; ++n) yacc[n] = (floatx4){0.f, 0.f, 0.f, 0.f};
    float mrun[4], lsum[4];
#pragma unroll
    for (int r = 0; r < 4; ++r) { mrun[r] = -1e30f; lsum[r] = 0.f; }

    const int nkb = ((q0 + 15) >> 6) + 1;

    for (int jb = 0; jb < nkb; ++jb) {
        const int kb0 = jb * 64;

        floatx4 s[4];
#pragma unroll
        for (int n = 0; n < 4; ++n) s[n] = (floatx4){0.f, 0.f, 0.f, 0.f};
#pragma unroll
        for (int n = 0; n < 4; ++n) {
            const __hip_bfloat16* kr = Kp + (size_t)(kb0 + 16 * n + c) * DH + 8 * g;
            short8 kf0 = *reinterpret_cast<const short8*>(kr);
            short8 kf1 = *reinterpret_cast<const short8*>(kr + 32);
            s[n] = __builtin_amdgcn_mfma_f32_16x16x32_bf16(qf0, kf0, s[n], 0, 0, 0);
            s[n] = __builtin_amdgcn_mfma_f32_16x16x32_bf16(qf1, kf1, s[n], 0, 0, 0);
        }

        if (kb0 + 63 > q0) {
#pragma unroll
            for (int n = 0; n < 4; ++n)
#pragma unroll
                for (int r = 0; r < 4; ++r)
                    if (kb0 + 16 * n + c > q0 + 4 * g + r) s[n][r] = -1e30f;
        }

        float mt[4];
#pragma unroll
        for (int r = 0; r < 4; ++r)
            mt[r] = fmaxf(fmaxf(s[0][r], s[1][r]), fmaxf(s[2][r], s[3][r]));
#pragma unroll
        for (int off = 8; off >= 1; off >>= 1)
#pragma unroll
            for (int r = 0; r < 4; ++r)
                mt[r] = fmaxf(mt[r], __shfl_xor(mt[r], off, 64));

        float corr[4];
#pragma unroll
        for (int r = 0; r < 4; ++r) {
            const float mn = fmaxf(mrun[r], mt[r]);
            corr[r] = __expf(mrun[r] - mn);
            mrun[r] = mn;
        }
#pragma unroll
        for (int n = 0; n < 4; ++n)
#pragma unroll
            for (int r = 0; r < 4; ++r) yacc[n][r] *= corr[r];

        float rs[4] = {0.f, 0.f, 0.f, 0.f};
#pragma unroll
        for (int n = 0; n < 4; ++n) {
            const int kf = n >> 1;
            const int gk = 2 * (n & 1) + (c >> 3);
            const int slot = gk ^ g;
#pragma unroll
            for (int r = 0; r < 4; ++r) {
                const float p = __expf(s[n][r] - mrun[r]);
                rs[r] += p;
                const int qrow = 4 * g + r;
                unsigned short bits = f2bf(p);
                *reinterpret_cast<unsigned short*>(
                    pw + kf * 1024 + qrow * 64 + (slot << 4) + (c & 7) * 2) = bits;
            }
        }
#pragma unroll
        for (int off = 8; off >= 1; off >>= 1)
#pragma unroll
            for (int r = 0; r < 4; ++r) rs[r] += __shfl_xor(rs[r], off, 64);
#pragma unroll
        for (int r = 0; r < 4; ++r) lsum[r] = lsum[r] * corr[r] + rs[r];

        asm volatile("s_waitcnt lgkmcnt(0)" ::: "memory");
        __builtin_amdgcn_sched_barrier(0);

        const int rslot = g ^ ((c >> 2) & 3);
        short8 pf0 = *reinterpret_cast<const short8*>(pw + c * 64 + (rslot << 4));
        short8 pf1 = *reinterpret_cast<const short8*>(pw + 1024 + c * 64 + (rslot << 4));

#pragma unroll
        for (int nd = 0; nd < 4; ++nd) {
            const __hip_bfloat16* vr = Vp + (size_t)(16 * nd + c) * T_SEQ + kb0 + 8 * g;
            short8 vf0 = *reinterpret_cast<const short8*>(vr);
            short8 vf1 = *reinterpret_cast<const short8*>(vr + 32);
            yacc[nd] = __builtin_amdgcn_mfma_f32_16x16x32_bf16(pf0, vf0, yacc[nd], 0, 0, 0);
            yacc[nd] = __builtin_amdgcn_mfma_f32_16x16x32_bf16(pf1, vf1, yacc[nd], 0, 0, 0);
        }
    }

    const int b = bh / NHEAD, h = bh % NHEAD;
    float inv[4];
#pragma unroll
    for (int r = 0; r < 4; ++r) inv[r] = 1.f / lsum[r];
#pragma unroll
    for (int n = 0; n < 4; ++n)
#pragma unroll
        for (int r = 0; r < 4; ++r) {
            unsigned short bits = f2bf(yacc[n][r] * inv[r]);
            y[((size_t)b * T_SEQ + q0 + 4 * g + r) * D_EMB + h * DH + 16 * n + c] =
                *reinterpret_cast<__hip_bfloat16*>(&bits);
        }
}

// ---------------------------------------------------------------------------
extern "C" void kernel_launch(void* const* d_in, const int* in_sizes, int n_in,
                              void* d_out, int out_size, void* d_ws, size_t ws_size,
                              hipStream_t stream)
{
    const float* x  = (const float*)d_in[0];
    const float* Wq = (const float*)d_in[1];
    const float* bq = (const float*)d_in[2];
    const float* Wk = (const float*)d_in[3];
    const float* bk = (const float*)d_in[4];
    const float* Wv = (const float*)d_in[5];
    const float* bv = (const float*)d_in[6];
    const float* Wp = (const float*)d_in[7];
    const float* bp = (const float*)d_in[8];
    float* out = (float*)d_out;

    // ws layout (bf16 elements): xb, wqkvb[2304][768], wpb, qb, kb, vtb, yb
    __hip_bfloat16* xb    = (__hip_bfloat16*)d_ws;
    __hip_bfloat16* wqkvb = xb + 6291456;
    __hip_bfloat16* wpb   = wqkvb + 1769472;
    __hip_bfloat16* qb    = wpb + 589824;
    __hip_bfloat16* kb    = qb + 6291456;
    __hip_bfloat16* vtb   = kb + 6291456;
    __hip_bfloat16* yb    = vtb + 6291456;   // total ~67.6 MB

    cast_bf16_kernel<<<4224, 256, 0, stream>>>(x, Wq, Wk, Wv, Wp, xb, wqkvb, wpb);

    gemm_bf16_mfma<0><<<dim3(64, 18), 256, 0, stream>>>(
        xb, wqkvb, bq, bk, bv, qb, kb, vtb, nullptr);

    attn_mfma_kernel<<<dim3(T_SEQ / 64, 4 * NHEAD), 256, 0, stream>>>(qb, kb, vtb, yb);

    gemm_bf16_mfma<1><<<dim3(64, 6), 256, 0, stream>>>(
        yb, wpb, bp, nullptr, nullptr, nullptr, nullptr, nullptr, out);
}

// Round 7
// 284.272 us; speedup vs baseline: 8.4758x; 1.8047x over previous
//
#include <hip/hip_runtime.h>
#include <hip/hip_bf16.h>
#include <cstddef>

#define T_SEQ 2048
#define D_EMB 768
#define NHEAD 12
#define DH 64

typedef __attribute__((ext_vector_type(8))) short short8;
typedef __attribute__((ext_vector_type(4))) short short4v;
typedef __attribute__((ext_vector_type(4))) float floatx4;

__device__ __forceinline__ unsigned short f2bf(float f) {
    unsigned u = __float_as_uint(f);
    u = (u + 0x7FFFu + ((u >> 16) & 1u)) >> 16;
    return (unsigned short)u;
}

__device__ __forceinline__ void gload16(const void* g, void* l) {
    __builtin_amdgcn_global_load_lds(
        (const __attribute__((address_space(1))) void*)g,
        (__attribute__((address_space(3))) void*)l, 16, 0, 0);
}

// ---------------------------------------------------------------------------
// Cast fp32 -> bf16 (unchanged from R5)
// ---------------------------------------------------------------------------
__global__ __launch_bounds__(256)
void cast_bf16_kernel(const float* __restrict__ x,
                      const float* __restrict__ Wq, const float* __restrict__ Wk,
                      const float* __restrict__ Wv, const float* __restrict__ Wp,
                      __hip_bfloat16* __restrict__ xb,
                      __hip_bfloat16* __restrict__ wqkvb,
                      __hip_bfloat16* __restrict__ wpb)
{
    const int ci = blockIdx.x * 256 + threadIdx.x;
    const float* src;
    __hip_bfloat16* dst;
    size_t off;
    if (ci < 786432) {
        src = x; dst = xb; off = (size_t)ci * 8;
    } else {
        const int r  = ci - 786432;
        const int wi = r / 73728;
        const int ro = r - wi * 73728;
        off = (size_t)ro * 8;
        src = (wi == 0) ? Wq : (wi == 1) ? Wk : (wi == 2) ? Wv : Wp;
        dst = (wi < 3) ? wqkvb + (size_t)wi * 589824 : wpb;
    }
    const float4* s4 = reinterpret_cast<const float4*>(src + off);
    const float4 f0 = s4[0], f1 = s4[1];
    unsigned short us[8] = { f2bf(f0.x), f2bf(f0.y), f2bf(f0.z), f2bf(f0.w),
                             f2bf(f1.x), f2bf(f1.y), f2bf(f1.z), f2bf(f1.w) };
    *reinterpret_cast<short8*>(dst + off) = *reinterpret_cast<const short8*>(us);
}

// ---------------------------------------------------------------------------
// bf16 MFMA GEMM (unchanged from R5)
// ---------------------------------------------------------------------------
template<int MODE>
__global__ __launch_bounds__(256)
void gemm_bf16_mfma(const __hip_bfloat16* __restrict__ A,
                    const __hip_bfloat16* __restrict__ Bm,
                    const float* __restrict__ b0, const float* __restrict__ b1,
                    const float* __restrict__ b2,
                    __hip_bfloat16* __restrict__ qo,
                    __hip_bfloat16* __restrict__ ko,
                    __hip_bfloat16* __restrict__ vo,
                    float* __restrict__ out)
{
    __shared__ __align__(16) __hip_bfloat16 As[128 * 64];
    __shared__ __align__(16) __hip_bfloat16 Bs[128 * 64];

    const int tid  = threadIdx.x;
    const int w    = tid >> 6, lane = tid & 63;
    const int g    = lane >> 4, c = lane & 15;
    const int m0   = blockIdx.x * 128, n0 = blockIdx.y * 128;
    const int wr   = w >> 1, wc = w & 1;
    const int srow = lane >> 3;
    const int scol = (lane & 7) * 8;

    floatx4 acc[4][4];
#pragma unroll
    for (int mi = 0; mi < 4; ++mi)
#pragma unroll
        for (int ni = 0; ni < 4; ++ni)
            acc[mi][ni] = (floatx4){0.f, 0.f, 0.f, 0.f};

    for (int kt = 0; kt < 12; ++kt) {
        const int k0 = kt * 64;
#pragma unroll
        for (int j = 0; j < 4; ++j) {
            const int ch = w * 4 + j;
            gload16(A  + (size_t)(m0 + ch * 8 + srow) * D_EMB + k0 + scol,
                    (char*)As + ch * 1024);
            gload16(Bm + (size_t)(n0 + ch * 8 + srow) * D_EMB + k0 + scol,
                    (char*)Bs + ch * 1024);
        }
        __syncthreads();
#pragma unroll
        for (int kk = 0; kk < 2; ++kk) {
            short8 af[4], bfr[4];
#pragma unroll
            for (int mi = 0; mi < 4; ++mi)
                af[mi] = *reinterpret_cast<const short8*>(
                    As + (wr * 64 + mi * 16 + c) * 64 + kk * 32 + g * 8);
#pragma unroll
            for (int ni = 0; ni < 4; ++ni)
                bfr[ni] = *reinterpret_cast<const short8*>(
                    Bs + (wc * 64 + ni * 16 + c) * 64 + kk * 32 + g * 8);
#pragma unroll
            for (int mi = 0; mi < 4; ++mi)
#pragma unroll
                for (int ni = 0; ni < 4; ++ni)
                    acc[mi][ni] = __builtin_amdgcn_mfma_f32_16x16x32_bf16(
                        af[mi], bfr[ni], acc[mi][ni], 0, 0, 0);
        }
        __syncthreads();
    }

    if (MODE == 0) {
        const int which = n0 / 768;
        const int nb    = n0 - which * 768 + wc * 64;
        const float* bias = (which == 0) ? b0 : (which == 1) ? b1 : b2;
        if (which < 2) {
            __hip_bfloat16* dst = (which == 0) ? qo : ko;
            const float scale = (which == 0) ? 0.125f : 1.0f;
#pragma unroll
            for (int mi = 0; mi < 4; ++mi) {
                const int m = m0 + wr * 64 + mi * 16 + 4 * g;
                const int b = m >> 11, t = m & 2047;
#pragma unroll
                for (int ni = 0; ni < 4; ++ni) {
                    const int n7 = nb + ni * 16 + c;
                    const int h = n7 >> 6, dh = n7 & 63;
                    const float bval = bias[n7];
                    const size_t base =
                        ((size_t)(b * NHEAD + h) * T_SEQ + t) * DH + dh;
#pragma unroll
                    for (int rr = 0; rr < 4; ++rr) {
                        unsigned short bits =
                            f2bf((acc[mi][ni][rr] + bval) * scale);
                        dst[base + (size_t)rr * DH] =
                            *reinterpret_cast<__hip_bfloat16*>(&bits);
                    }
                }
            }
        } else {
#pragma unroll
            for (int mi = 0; mi < 4; ++mi) {
                const int m = m0 + wr * 64 + mi * 16 + 4 * g;
                const int b = m >> 11, t = m & 2047;
#pragma unroll
                for (int ni = 0; ni < 4; ++ni) {
                    const int n7 = nb + ni * 16 + c;
                    const int h = n7 >> 6, dh = n7 & 63;
                    const float bval = bias[n7];
                    unsigned short us[4];
#pragma unroll
                    for (int rr = 0; rr < 4; ++rr)
                        us[rr] = f2bf(acc[mi][ni][rr] + bval);
                    *reinterpret_cast<short4v*>(
                        vo + ((size_t)(b * NHEAD + h) * DH + dh) * T_SEQ + t) =
                        *reinterpret_cast<const short4v*>(us);
                }
            }
        }
    } else {
#pragma unroll
        for (int mi = 0; mi < 4; ++mi) {
            const int m = m0 + wr * 64 + mi * 16 + 4 * g;
#pragma unroll
            for (int ni = 0; ni < 4; ++ni) {
                const int n = n0 + wc * 64 + ni * 16 + c;
                const float bval = b0[n];
#pragma unroll
                for (int rr = 0; rr < 4; ++rr)
                    out[(size_t)(m + rr) * D_EMB + n] = acc[mi][ni][rr] + bval;
            }
        }
    }
}

// ---------------------------------------------------------------------------
// MFMA flash attention v2: cooperative double-buffered LDS staging of K and
// V^T tiles (XOR-swizzled: lds slot = global slot ^ (row&7), staged via
// inverse-swizzled global source + linear global_load_lds dest), prefetch
// issued before compute (2-phase), LPT + XCD-aware block mapping
// (xcd = fid&7 owns 6 heads; q-tiles descending within each head).
// Per wave: 16 q-rows, softmax/P-roundtrip/PV identical to R4/R5.
// ---------------------------------------------------------------------------
__global__ __launch_bounds__(256)
void attn_mfma_kernel(const __hip_bfloat16* __restrict__ qb,
                      const __hip_bfloat16* __restrict__ kbp,
                      const __hip_bfloat16* __restrict__ vtb,
                      __hip_bfloat16* __restrict__ y)
{
    __shared__ __align__(16) char Ksh[2][8192];   // [64 key-rows][8 slots x16B]
    __shared__ __align__(16) char Vsh[2][8192];   // V^T: [64 dh-rows][8 slots]
    __shared__ __align__(16) char Pbuf[4][2048];

    // --- LPT + XCD mapping: 1536 blocks = 8 XCDs x (6 heads x 32 q-tiles) ---
    const int fid = blockIdx.x;
    const int xcd = fid & 7;
    const int ix  = fid >> 3;            // 0..191
    const int bh  = xcd * 6 + (ix >> 5); // 6 heads per XCD (3MB K/V < 4MB L2)
    const int qt  = 31 - (ix & 31);      // longest blocks first

    const int w    = threadIdx.x >> 6;
    const int lane = threadIdx.x & 63;
    const int g    = lane >> 4;
    const int c    = lane & 15;
    const int q0   = qt * 64 + w * 16;

    const __hip_bfloat16* Qp = qb  + (size_t)bh * T_SEQ * DH;
    const char* Kg0 = (const char*)(kbp + (size_t)bh * T_SEQ * DH);
    const char* Vg0 = (const char*)(vtb + (size_t)bh * DH * T_SEQ);
    char* pw = Pbuf[w];

    short8 qf0 = *reinterpret_cast<const short8*>(Qp + (size_t)(q0 + c) * DH + 8 * g);
    short8 qf1 = *reinterpret_cast<const short8*>(Qp + (size_t)(q0 + c) * DH + 32 + 8 * g);

    floatx4 yacc[4];
#pragma unroll
    for (int n = 0; n < 4; ++n) yacc[n] = (floatx4){0.f, 0.f, 0.f, 0.f};
    float mrun[4], lsum[4];
#pragma unroll
    for (int r = 0; r < 4; ++r) { mrun[r] = -1e30f; lsum[r] = 0.f; }

    const int nkb = qt + 1;

    // stage tile kb0 into buffer buf: 512 chunks of 16B each for K and V^T.
    // lds chunk (row r, slot s) <- global chunk (r, s ^ (r&7)); dest linear.
    auto stage = [&](int buf, int kb0) {
        const char* Kg = Kg0 + (size_t)kb0 * 128;  // key row stride 128B
        const char* Vg = Vg0 + (size_t)kb0 * 2;    // V^T col offset
#pragma unroll
        for (int i = 0; i < 2; ++i) {
            const int chb = i * 256 + w * 64;      // wave-uniform chunk base
            const int ch  = chb + lane;
            const int r   = ch >> 3;
            const int sg  = (ch & 7) ^ (r & 7);
            gload16(Kg + (size_t)r * 128  + sg * 16, Ksh[buf] + chb * 16);
            gload16(Vg + (size_t)r * 4096 + sg * 16, Vsh[buf] + chb * 16);
        }
    };

    stage(0, 0);
    __syncthreads();
    int cur = 0;

    for (int jb = 0; jb < nkb; ++jb) {
        if (jb + 1 < nkb) stage(cur ^ 1, (jb + 1) * 64);  // prefetch first

        const char* Kb = Ksh[cur];
        const char* Vb = Vsh[cur];
        const int kb0 = jb * 64;

        // ---- S = Q K^T ----
        floatx4 s[4];
#pragma unroll
        for (int n = 0; n < 4; ++n) s[n] = (floatx4){0.f, 0.f, 0.f, 0.f};
#pragma unroll
        for (int n = 0; n < 4; ++n) {
            const int rb = (16 * n + c) * 128;
            short8 kf0 = *reinterpret_cast<const short8*>(
                Kb + rb + ((g ^ (c & 7)) << 4));
            short8 kf1 = *reinterpret_cast<const short8*>(
                Kb + rb + (((4 + g) ^ (c & 7)) << 4));
            s[n] = __builtin_amdgcn_mfma_f32_16x16x32_bf16(qf0, kf0, s[n], 0, 0, 0);
            s[n] = __builtin_amdgcn_mfma_f32_16x16x32_bf16(qf1, kf1, s[n], 0, 0, 0);
        }

        // ---- causal mask (only the diagonal tile jb==qt) ----
        if (jb == qt) {
#pragma unroll
            for (int n = 0; n < 4; ++n)
#pragma unroll
                for (int r = 0; r < 4; ++r)
                    if (kb0 + 16 * n + c > q0 + 4 * g + r) s[n][r] = -1e30f;
        }

        // ---- online softmax ----
        float mt[4];
#pragma unroll
        for (int r = 0; r < 4; ++r)
            mt[r] = fmaxf(fmaxf(s[0][r], s[1][r]), fmaxf(s[2][r], s[3][r]));
#pragma unroll
        for (int off = 8; off >= 1; off >>= 1)
#pragma unroll
            for (int r = 0; r < 4; ++r)
                mt[r] = fmaxf(mt[r], __shfl_xor(mt[r], off, 64));

        float corr[4];
#pragma unroll
        for (int r = 0; r < 4; ++r) {
            const float mn = fmaxf(mrun[r], mt[r]);
            corr[r] = __expf(mrun[r] - mn);
            mrun[r] = mn;
        }
#pragma unroll
        for (int n = 0; n < 4; ++n)
#pragma unroll
            for (int r = 0; r < 4; ++r) yacc[n][r] *= corr[r];

        float rs[4] = {0.f, 0.f, 0.f, 0.f};
#pragma unroll
        for (int n = 0; n < 4; ++n) {
            const int kf = n >> 1;
            const int gk = 2 * (n & 1) + (c >> 3);
            const int slot = gk ^ g;
#pragma unroll
            for (int r = 0; r < 4; ++r) {
                const float p = __expf(s[n][r] - mrun[r]);
                rs[r] += p;
                const int qrow = 4 * g + r;
                unsigned short bits = f2bf(p);
                *reinterpret_cast<unsigned short*>(
                    pw + kf * 1024 + qrow * 64 + (slot << 4) + (c & 7) * 2) = bits;
            }
        }
#pragma unroll
        for (int off = 8; off >= 1; off >>= 1)
#pragma unroll
            for (int r = 0; r < 4; ++r) rs[r] += __shfl_xor(rs[r], off, 64);
#pragma unroll
        for (int r = 0; r < 4; ++r) lsum[r] = lsum[r] * corr[r] + rs[r];

        asm volatile("s_waitcnt lgkmcnt(0)" ::: "memory");
        __builtin_amdgcn_sched_barrier(0);

        const int rslot = g ^ ((c >> 2) & 3);
        short8 pf0 = *reinterpret_cast<const short8*>(pw + c * 64 + (rslot << 4));
        short8 pf1 = *reinterpret_cast<const short8*>(pw + 1024 + c * 64 + (rslot << 4));

        // ---- PV from swizzled V^T LDS tile ----
#pragma unroll
        for (int nd = 0; nd < 4; ++nd) {
            const int rb = (16 * nd + c) * 128;
            short8 vf0 = *reinterpret_cast<const short8*>(
                Vb + rb + ((g ^ (c & 7)) << 4));
            short8 vf1 = *reinterpret_cast<const short8*>(
                Vb + rb + (((4 + g) ^ (c & 7)) << 4));
            yacc[nd] = __builtin_amdgcn_mfma_f32_16x16x32_bf16(pf0, vf0, yacc[nd], 0, 0, 0);
            yacc[nd] = __builtin_amdgcn_mfma_f32_16x16x32_bf16(pf1, vf1, yacc[nd], 0, 0, 0);
        }

        __syncthreads();   // prefetch landed (vmcnt drained) + buf reads done
        cur ^= 1;
    }

    const int b = bh / NHEAD, h = bh % NHEAD;
    float inv[4];
#pragma unroll
    for (int r = 0; r < 4; ++r) inv[r] = 1.f / lsum[r];
#pragma unroll
    for (int n = 0; n < 4; ++n)
#pragma unroll
        for (int r = 0; r < 4; ++r) {
            unsigned short bits = f2bf(yacc[n][r] * inv[r]);
            y[((size_t)b * T_SEQ + q0 + 4 * g + r) * D_EMB + h * DH + 16 * n + c] =
                *reinterpret_cast<__hip_bfloat16*>(&bits);
        }
}

// ---------------------------------------------------------------------------
extern "C" void kernel_launch(void* const* d_in, const int* in_sizes, int n_in,
                              void* d_out, int out_size, void* d_ws, size_t ws_size,
                              hipStream_t stream)
{
    const float* x  = (const float*)d_in[0];
    const float* Wq = (const float*)d_in[1];
    const float* bq = (const float*)d_in[2];
    const float* Wk = (const float*)d_in[3];
    const float* bk = (const float*)d_in[4];
    const float* Wv = (const float*)d_in[5];
    const float* bv = (const float*)d_in[6];
    const float* Wp = (const float*)d_in[7];
    const float* bp = (const float*)d_in[8];
    float* out = (float*)d_out;

    __hip_bfloat16* xb    = (__hip_bfloat16*)d_ws;
    __hip_bfloat16* wqkvb = xb + 6291456;
    __hip_bfloat16* wpb   = wqkvb + 1769472;
    __hip_bfloat16* qb    = wpb + 589824;
    __hip_bfloat16* kb    = qb + 6291456;
    __hip_bfloat16* vtb   = kb + 6291456;
    __hip_bfloat16* yb    = vtb + 6291456;

    cast_bf16_kernel<<<4224, 256, 0, stream>>>(x, Wq, Wk, Wv, Wp, xb, wqkvb, wpb);

    gemm_bf16_mfma<0><<<dim3(64, 18), 256, 0, stream>>>(
        xb, wqkvb, bq, bk, bv, qb, kb, vtb, nullptr);

    attn_mfma_kernel<<<1536, 256, 0, stream>>>(qb, kb, vtb, yb);

    gemm_bf16_mfma<1><<<dim3(64, 6), 256, 0, stream>>>(
        yb, wpb, bp, nullptr, nullptr, nullptr, nullptr, nullptr, out);
}